// Round 2
// baseline (797.350 us; speedup 1.0000x reference)
//
#include <hip/hip_runtime.h>
#include <hip/hip_bf16.h>

// Problem: B=4, T=2048, C=1024, H=16, HD=64.  fp32 I/O per reference.
// Pipeline: GEMM1 (qkv = x@Wqkv, fp32->bf16) -> flash attention (bf16) ->
// GEMM2 (out = a@Wout + bout, fp32 out).  MFMA bf16 with fp32 accumulation.

typedef __bf16 bf16;
typedef __bf16 bf16x8 __attribute__((ext_vector_type(8)));
typedef float floatx4 __attribute__((ext_vector_type(4)));

#define MFMA16(a, b, c) __builtin_amdgcn_mfma_f32_16x16x32_bf16(a, b, c, 0, 0, 0)

static __device__ __forceinline__ float rmax16(float v) {
#pragma unroll
  for (int m = 1; m < 16; m <<= 1) v = fmaxf(v, __shfl_xor(v, m));
  return v;
}
static __device__ __forceinline__ float rsum16(float v) {
#pragma unroll
  for (int m = 1; m < 16; m <<= 1) v += __shfl_xor(v, m);
  return v;
}

// ---------------------------------------------------------------------------
// GEMM: C[M,N] = A[M,K] @ B[K,N] (+bias), fp32 accum, bf16 MFMA.
// A_BF16: A is bf16 (else fp32, converted on stage).  B always fp32 in.
// OUT_BF16: C stored bf16 (else fp32).
// Tiles: 128x128 block, BK=32, 256 threads = 4 waves 2x2, wave = 64x64 via
// 4x4 frags of mfma_f32_16x16x32_bf16.
// ---------------------------------------------------------------------------
template <bool A_BF16, bool OUT_BF16>
__global__ __launch_bounds__(256)
void gemm_mixed(const void* __restrict__ Av, const float* __restrict__ B,
                const float* __restrict__ bias, void* __restrict__ Cv,
                int M, int N, int K) {
  __shared__ __align__(16) bf16 As[128][40];  // [m][k], +8 pad
  __shared__ __align__(16) bf16 Bs[128][40];  // [n][k] transposed, +8 pad

  const int t = threadIdx.x;
  const int lane = t & 63;
  const int wave = t >> 6;
  const int m_ = lane & 15;
  const int quad = lane >> 4;
  const int wm = wave >> 1, wn = wave & 1;
  const int m0 = blockIdx.y * 128, n0 = blockIdx.x * 128;

  floatx4 acc[4][4];
#pragma unroll
  for (int i = 0; i < 4; ++i)
#pragma unroll
    for (int j = 0; j < 4; ++j) {
      floatx4 z = {0.f, 0.f, 0.f, 0.f};
      acc[i][j] = z;
    }

  for (int k0 = 0; k0 < K; k0 += 32) {
    // --- Stage A tile: 128 rows x 32 k, as 512 groups of 8 elements
#pragma unroll
    for (int c = t; c < 512; c += 256) {
      int row = c >> 2, kg = c & 3;
      if (A_BF16) {
        const bf16* Ab = (const bf16*)Av;
        bf16x8 v = *(const bf16x8*)(Ab + (size_t)(m0 + row) * K + k0 + kg * 8);
        *(bf16x8*)(&As[row][kg * 8]) = v;
      } else {
        const float* Af = (const float*)Av;
        const float* src = Af + (size_t)(m0 + row) * K + k0 + kg * 8;
        float4 f0 = *(const float4*)(src);
        float4 f1 = *(const float4*)(src + 4);
        bf16x8 v;
        v[0] = (bf16)f0.x; v[1] = (bf16)f0.y; v[2] = (bf16)f0.z; v[3] = (bf16)f0.w;
        v[4] = (bf16)f1.x; v[5] = (bf16)f1.y; v[6] = (bf16)f1.z; v[7] = (bf16)f1.w;
        *(bf16x8*)(&As[row][kg * 8]) = v;
      }
    }
    // --- Stage B tile transposed: 32 k-rows x 128 n
#pragma unroll
    for (int c = t; c < 512; c += 256) {
      int kr = c >> 4, ng = c & 15;
      const float* src = B + (size_t)(k0 + kr) * N + n0 + ng * 8;
      float4 f0 = *(const float4*)(src);
      float4 f1 = *(const float4*)(src + 4);
      Bs[ng * 8 + 0][kr] = (bf16)f0.x;
      Bs[ng * 8 + 1][kr] = (bf16)f0.y;
      Bs[ng * 8 + 2][kr] = (bf16)f0.z;
      Bs[ng * 8 + 3][kr] = (bf16)f0.w;
      Bs[ng * 8 + 4][kr] = (bf16)f1.x;
      Bs[ng * 8 + 5][kr] = (bf16)f1.y;
      Bs[ng * 8 + 6][kr] = (bf16)f1.z;
      Bs[ng * 8 + 7][kr] = (bf16)f1.w;
    }
    __syncthreads();

    bf16x8 af[4], bfr[4];
#pragma unroll
    for (int mt = 0; mt < 4; ++mt)
      af[mt] = *(const bf16x8*)(&As[wm * 64 + mt * 16 + m_][quad * 8]);
#pragma unroll
    for (int nt = 0; nt < 4; ++nt)
      bfr[nt] = *(const bf16x8*)(&Bs[wn * 64 + nt * 16 + m_][quad * 8]);
#pragma unroll
    for (int mt = 0; mt < 4; ++mt)
#pragma unroll
      for (int nt = 0; nt < 4; ++nt)
        acc[mt][nt] = MFMA16(af[mt], bfr[nt], acc[mt][nt]);
    __syncthreads();
  }

  // --- Epilogue: C/D layout row = quad*4+r, col = lane&15
#pragma unroll
  for (int mt = 0; mt < 4; ++mt) {
#pragma unroll
    for (int nt = 0; nt < 4; ++nt) {
      int col = n0 + wn * 64 + nt * 16 + m_;
      float bv = bias ? bias[col] : 0.f;
#pragma unroll
      for (int r = 0; r < 4; ++r) {
        int row = m0 + wm * 64 + mt * 16 + quad * 4 + r;
        float val = acc[mt][nt][r] + bv;
        if (OUT_BF16)
          ((bf16*)Cv)[(size_t)row * N + col] = (bf16)val;
        else
          ((float*)Cv)[(size_t)row * N + col] = val;
      }
    }
  }
}

// ---------------------------------------------------------------------------
// Flash attention fwd, causal.  qkv (bf16): [B,T,3C] rows of 3072; head h:
// q at col h*64, k at 1024+h*64, v at 2048+h*64.  One wave per 16-query tile,
// 32-key chunks, online softmax.  attnout: [B,T,C] bf16.
// ---------------------------------------------------------------------------
__global__ __launch_bounds__(256)
void attn_fwd(const bf16* __restrict__ qkv, bf16* __restrict__ attnout) {
  const int lane = threadIdx.x & 63;
  const int wave = threadIdx.x >> 6;
  const int gw = blockIdx.x * 4 + wave;   // 0..8191
  const int qtile = gw & 127;             // 0..127 (T/16)
  const int bh = gw >> 7;                 // 0..63
  const int b = bh >> 4, h = bh & 15;
  const int m_ = lane & 15, quad = lane >> 4;

  const bf16* base = qkv + (size_t)b * 2048 * 3072;
  const bf16* Qp = base + h * 64;
  const bf16* Kp = base + 1024 + h * 64;
  const bf16* Vp = base + 2048 + h * 64;

  __shared__ __align__(16) bf16 Plds[4][16][40];  // per-wave P tile [m][k]

  // Q fragment (A layout): row m = lane&15, k = c*32 + quad*8 + j
  const int qrow = qtile * 16 + m_;
  const bf16x8 qf0 = *(const bf16x8*)(Qp + (size_t)qrow * 3072 + quad * 8);
  const bf16x8 qf1 = *(const bf16x8*)(Qp + (size_t)qrow * 3072 + 32 + quad * 8);

  floatx4 o[4];
#pragma unroll
  for (int i = 0; i < 4; ++i) {
    floatx4 z = {0.f, 0.f, 0.f, 0.f};
    o[i] = z;
  }
  float mrow[4] = {-1e30f, -1e30f, -1e30f, -1e30f};
  float lrow[4] = {0.f, 0.f, 0.f, 0.f};

  const int kmax = qtile * 16 + 15;
  for (int kb = 0; kb <= kmax; kb += 32) {
    // --- S = Q K^T: two 16x16 key tiles, head-dim 64 = 2 mfma steps each
    floatx4 s0 = {0.f, 0.f, 0.f, 0.f}, s1 = {0.f, 0.f, 0.f, 0.f};
    {
      const int kr0 = kb + m_;
      const bf16x8 ka = *(const bf16x8*)(Kp + (size_t)kr0 * 3072 + quad * 8);
      const bf16x8 kb_ = *(const bf16x8*)(Kp + (size_t)kr0 * 3072 + 32 + quad * 8);
      s0 = MFMA16(qf0, ka, s0);
      s0 = MFMA16(qf1, kb_, s0);
      const int kr1 = kb + 16 + m_;
      const bf16x8 kc = *(const bf16x8*)(Kp + (size_t)kr1 * 3072 + quad * 8);
      const bf16x8 kd = *(const bf16x8*)(Kp + (size_t)kr1 * 3072 + 32 + quad * 8);
      s1 = MFMA16(qf0, kc, s1);
      s1 = MFMA16(qf1, kd, s1);
    }
    // --- online softmax (C/D layout: row = quad*4+r, col = m_)
#pragma unroll
    for (int r = 0; r < 4; ++r) {
      const int qr = qtile * 16 + quad * 4 + r;
      float a0 = s0[r] * 0.125f;
      float a1 = s1[r] * 0.125f;
      if (kb + m_ > qr) a0 = -1e30f;
      if (kb + 16 + m_ > qr) a1 = -1e30f;
      float mx = rmax16(fmaxf(a0, a1));
      float mnew = fmaxf(mrow[r], mx);
      float alpha = __expf(mrow[r] - mnew);
      float p0 = __expf(a0 - mnew);
      float p1 = __expf(a1 - mnew);
      lrow[r] = lrow[r] * alpha + rsum16(p0 + p1);
      mrow[r] = mnew;
#pragma unroll
      for (int nt = 0; nt < 4; ++nt) o[nt][r] *= alpha;
      Plds[wave][quad * 4 + r][m_] = (bf16)p0;
      Plds[wave][quad * 4 + r][16 + m_] = (bf16)p1;
    }
    // --- PV: P [16m x 32k] (A layout via LDS) x V [32k x 64n]
    const bf16x8 pf = *(const bf16x8*)(&Plds[wave][m_][quad * 8]);
#pragma unroll
    for (int nt = 0; nt < 4; ++nt) {
      bf16x8 vf;
#pragma unroll
      for (int j = 0; j < 8; ++j)
        vf[j] = Vp[(size_t)(kb + quad * 8 + j) * 3072 + nt * 16 + m_];
      o[nt] = MFMA16(pf, vf, o[nt]);
    }
  }

  // --- normalize + store [B,T,H*HD]
#pragma unroll
  for (int r = 0; r < 4; ++r) {
    const float inv = 1.0f / lrow[r];
    const int trow = qtile * 16 + quad * 4 + r;
    const size_t orow = ((size_t)b * 2048 + trow) * 1024 + h * 64;
#pragma unroll
    for (int nt = 0; nt < 4; ++nt)
      attnout[orow + nt * 16 + m_] = (bf16)(o[nt][r] * inv);
  }
}

// ---------------------------------------------------------------------------
extern "C" void kernel_launch(void* const* d_in, const int* in_sizes, int n_in,
                              void* d_out, int out_size, void* d_ws, size_t ws_size,
                              hipStream_t stream) {
  (void)in_sizes; (void)n_in; (void)out_size; (void)ws_size;
  const float* x    = (const float*)d_in[0];   // [4,2048,1024] fp32
  // d_in[1] = causal_mask (unused; causality applied analytically)
  const float* Wqkv = (const float*)d_in[2];   // [1024,3072] fp32
  const float* Wout = (const float*)d_in[3];   // [1024,1024] fp32
  const float* bout = (const float*)d_in[4];   // [1024] fp32
  float* out = (float*)d_out;                  // [4,2048,1024] fp32

  bf16* qkv     = (bf16*)d_ws;                                     // 48 MiB
  bf16* attnout = (bf16*)((char*)d_ws + (size_t)8192 * 3072 * 2);  // 16 MiB

  // GEMM1: qkv = x @ Wqkv   (M=8192, N=3072, K=1024), fp32 in, bf16 out
  gemm_mixed<false, true><<<dim3(3072 / 128, 8192 / 128), 256, 0, stream>>>(
      x, Wqkv, nullptr, qkv, 8192, 3072, 1024);

  // Flash attention: 64 head-batches * 128 q-tiles / 4 waves per block
  attn_fwd<<<2048, 256, 0, stream>>>(qkv, attnout);

  // GEMM2: out = attnout @ Wout + bout  (M=8192, N=1024, K=1024), fp32 out
  gemm_mixed<true, false><<<dim3(1024 / 128, 8192 / 128), 256, 0, stream>>>(
      attnout, Wout, bout, out, 8192, 1024, 1024);
}

// Round 3
// 425.584 us; speedup vs baseline: 1.8735x; 1.8735x over previous
//
#include <hip/hip_runtime.h>
#include <hip/hip_bf16.h>
#include <stdint.h>

// B=4, T=2048, C=1024, H=16, HD=64.  fp32 I/O.
// Prologue: x->bf16, Wqkv->bf16 [N][K], into d_out scratch (dead before GEMM2).
// GEMM1 (m97-style bf16 gemm_bt) -> flash attn (LDS-staged K/V^T) ->
// transpose Wout into dead qkv region -> GEMM2 (fp32 out + bias).

typedef __bf16 bf16;
typedef __bf16 bf16x4 __attribute__((ext_vector_type(4)));
typedef __bf16 bf16x8 __attribute__((ext_vector_type(8)));
typedef float floatx4 __attribute__((ext_vector_type(4)));

#define MFMA16(a, b, c) __builtin_amdgcn_mfma_f32_16x16x32_bf16(a, b, c, 0, 0, 0)

#if defined(__has_builtin)
#if __has_builtin(__builtin_amdgcn_global_load_lds)
#define HAS_GLL 1
#endif
#endif

#ifdef HAS_GLL
__device__ __forceinline__ void gll16(const bf16* g, bf16* l) {
  __builtin_amdgcn_global_load_lds(
      (const __attribute__((address_space(1))) unsigned int*)g,
      (__attribute__((address_space(3))) unsigned int*)l, 16, 0, 0);
}
#endif

static __device__ __forceinline__ float rmax16(float v) {
#pragma unroll
  for (int m = 1; m < 16; m <<= 1) v = fmaxf(v, __shfl_xor(v, m));
  return v;
}
static __device__ __forceinline__ float rsum16(float v) {
#pragma unroll
  for (int m = 1; m < 16; m <<= 1) v += __shfl_xor(v, m);
  return v;
}

// --------------------------------------------------------------------------
// fp32 -> bf16 elementwise (8 elems/thread)
// --------------------------------------------------------------------------
__global__ __launch_bounds__(256)
void convert_x(const float* __restrict__ in, bf16* __restrict__ out) {
  const size_t i = (size_t)blockIdx.x * 256 + threadIdx.x;
  const float4* p = (const float4*)in + i * 2;
  float4 a = p[0], b = p[1];
  bf16x8 v;
  v[0] = (bf16)a.x; v[1] = (bf16)a.y; v[2] = (bf16)a.z; v[3] = (bf16)a.w;
  v[4] = (bf16)b.x; v[5] = (bf16)b.y; v[6] = (bf16)b.z; v[7] = (bf16)b.w;
  *((bf16x8*)out + i) = v;
}

// --------------------------------------------------------------------------
// W[K][N] fp32 -> Wt[N][K] bf16, 32x32 tiles
// --------------------------------------------------------------------------
__global__ __launch_bounds__(256)
void transpose_w(const float* __restrict__ W, bf16* __restrict__ Wt, int K, int N) {
  __shared__ bf16 tile[32][33];
  const int k0 = blockIdx.y * 32, n0 = blockIdx.x * 32;
  const int t = threadIdx.x;
  {
    const int r = t >> 3, c4 = (t & 7) * 4;
    float4 v = *(const float4*)(W + (size_t)(k0 + r) * N + n0 + c4);
    tile[r][c4 + 0] = (bf16)v.x;
    tile[r][c4 + 1] = (bf16)v.y;
    tile[r][c4 + 2] = (bf16)v.z;
    tile[r][c4 + 3] = (bf16)v.w;
  }
  __syncthreads();
  {
    const int nr = t >> 3, kc = (t & 7) * 4;
    bf16x4 o;
#pragma unroll
    for (int j = 0; j < 4; ++j) o[j] = tile[kc + j][nr];
    *(bf16x4*)(Wt + (size_t)(n0 + nr) * K + k0 + kc) = o;
  }
}

// --------------------------------------------------------------------------
// GEMM: C[M,N] = A[M,K] @ Bt[N,K]^T (+bias), both bf16, fp32 accum.
// 128x128 tile, BK=32, 4 waves 2x2, wave 64x64 via 4x4 mfma 16x16x32 frags.
// LDS [row][32] with column-group XOR swizzle (cg = kg ^ (row&3)) so frag
// ds_read_b128 is 4-way (floor) instead of 8-way.  global_load_lds staging.
// --------------------------------------------------------------------------
template <bool OUT_BF16>
__global__ __launch_bounds__(256, 2)
void gemm_bt(const bf16* __restrict__ A, const bf16* __restrict__ Bt,
             const float* __restrict__ bias, void* __restrict__ Cv,
             int M, int N, int K) {
  __shared__ __align__(16) bf16 As[128 * 32];
  __shared__ __align__(16) bf16 Bs[128 * 32];

  const int t = threadIdx.x, lane = t & 63, w = t >> 6;
  const int m_ = lane & 15, quad = lane >> 4;
  const int wm = w >> 1, wn = w & 1;
  const int m0 = blockIdx.y * 128, n0 = blockIdx.x * 128;

  floatx4 acc[4][4];
#pragma unroll
  for (int i = 0; i < 4; ++i)
#pragma unroll
    for (int j = 0; j < 4; ++j) {
      floatx4 z = {0.f, 0.f, 0.f, 0.f};
      acc[i][j] = z;
    }

  const int srow = w * 32 + (lane >> 2);  // +16 for second instr
  const int kg = lane & 3;

  for (int k0 = 0; k0 < K; k0 += 32) {
#pragma unroll
    for (int j = 0; j < 2; ++j) {
      const int R = srow + j * 16;
      const int cg = kg ^ (R & 3);
      const bf16* ga = A + (size_t)(m0 + R) * K + k0 + cg * 8;
      const bf16* gb = Bt + (size_t)(n0 + R) * K + k0 + cg * 8;
#ifdef HAS_GLL
      gll16(ga, As + (size_t)(w * 32 + j * 16) * 32);
      gll16(gb, Bs + (size_t)(w * 32 + j * 16) * 32);
#else
      *(bf16x8*)(As + (size_t)R * 32 + kg * 8) = *(const bf16x8*)ga;
      *(bf16x8*)(Bs + (size_t)R * 32 + kg * 8) = *(const bf16x8*)gb;
#endif
    }
    __syncthreads();

    bf16x8 af[4], bfr[4];
#pragma unroll
    for (int mt = 0; mt < 4; ++mt) {
      const int r = wm * 64 + mt * 16 + m_;
      const int cg = quad ^ (r & 3);
      af[mt] = *(const bf16x8*)(As + (size_t)r * 32 + cg * 8);
    }
#pragma unroll
    for (int nt = 0; nt < 4; ++nt) {
      const int rn = wn * 64 + nt * 16 + m_;
      const int cg = quad ^ (rn & 3);
      bfr[nt] = *(const bf16x8*)(Bs + (size_t)rn * 32 + cg * 8);
    }
#pragma unroll
    for (int mt = 0; mt < 4; ++mt)
#pragma unroll
      for (int nt = 0; nt < 4; ++nt)
        acc[mt][nt] = MFMA16(af[mt], bfr[nt], acc[mt][nt]);
    __syncthreads();
  }

#pragma unroll
  for (int mt = 0; mt < 4; ++mt)
#pragma unroll
    for (int nt = 0; nt < 4; ++nt) {
      const int col = n0 + wn * 64 + nt * 16 + m_;
      const float bv = bias ? bias[col] : 0.f;
#pragma unroll
      for (int r = 0; r < 4; ++r) {
        const int row = m0 + wm * 64 + mt * 16 + quad * 4 + r;
        const float val = acc[mt][nt][r] + bv;
        if (OUT_BF16)
          ((bf16*)Cv)[(size_t)row * N + col] = (bf16)val;
        else
          ((float*)Cv)[(size_t)row * N + col] = val;
      }
    }
}

// --------------------------------------------------------------------------
// Flash attention, causal.  Block = (head, 128 queries): grid (16, 64).
// 4 waves x 32 queries (2 m-tiles).  Per 64-key chunk: K staged [key][d]
// (stride 88), V staged transposed [d][key] (stride 88); all frag reads
// ds_read_b128; P via per-wave LDS round-trip (C-layout -> A-layout).
// --------------------------------------------------------------------------
__global__ __launch_bounds__(256, 2)
void attn_fwd(const bf16* __restrict__ qkv, bf16* __restrict__ attnout) {
  constexpr int KS = 88;  // LDS row stride: 176B, 16B-aligned, conflict-floor
  __shared__ __align__(16) bf16 Ks[64 * KS];
  __shared__ __align__(16) bf16 VT[64 * KS];
  __shared__ __align__(16) bf16 Pl[8 * 16 * KS];  // [wave*2+mt][16][KS]

  const int t = threadIdx.x, lane = t & 63, w = t >> 6;
  const int m_ = lane & 15, quad = lane >> 4;
  const int qb = blockIdx.x;  // 0..15 (128-query block)
  const int bh = blockIdx.y;  // 0..63
  const int b = bh >> 4, h = bh & 15;

  const bf16* base = qkv + (size_t)b * 2048 * 3072;
  const bf16* Qp = base + h * 64;
  const bf16* Kp = base + 1024 + h * 64;
  const bf16* Vp = base + 2048 + h * 64;
  const int q0w = qb * 128 + w * 32;

  // Q fragments (A layout): [mt][kc]
  bf16x8 qf[2][2];
#pragma unroll
  for (int mt = 0; mt < 2; ++mt)
#pragma unroll
    for (int kc = 0; kc < 2; ++kc)
      qf[mt][kc] = *(const bf16x8*)(Qp + (size_t)(q0w + mt * 16 + m_) * 3072 +
                                    kc * 32 + quad * 8);

  floatx4 o[2][4];
#pragma unroll
  for (int mt = 0; mt < 2; ++mt)
#pragma unroll
    for (int nt = 0; nt < 4; ++nt) {
      floatx4 z = {0.f, 0.f, 0.f, 0.f};
      o[mt][nt] = z;
    }
  float mrow[2][4], lrow[2][4];
#pragma unroll
  for (int mt = 0; mt < 2; ++mt)
#pragma unroll
    for (int r = 0; r < 4; ++r) { mrow[mt][r] = -1e30f; lrow[mt][r] = 0.f; }

  const int nchunks = 2 * qb + 2;
  for (int ch = 0; ch < nchunks; ++ch) {
    const int kb = ch * 64;
    // --- stage K [key][d], b128 writes (2-way max)
#pragma unroll
    for (int i = 0; i < 2; ++i) {
      const int c = t + 256 * i;
      const int kk = c >> 3, dg = c & 7;
      bf16x8 v = *(const bf16x8*)(Kp + (size_t)(kb + kk) * 3072 + dg * 8);
      *(bf16x8*)(Ks + (size_t)kk * KS + dg * 8) = v;
    }
    // --- stage V transposed [d][key], scalar writes (2-way: adjacent keys
    // share a dword)
    {
      const int kk = t & 63;
#pragma unroll
      for (int i = 0; i < 2; ++i) {
        const int dg = (t >> 6) + 4 * i;
        bf16x8 v = *(const bf16x8*)(Vp + (size_t)(kb + kk) * 3072 + dg * 8);
#pragma unroll
        for (int j = 0; j < 8; ++j) VT[(size_t)(dg * 8 + j) * KS + kk] = v[j];
      }
    }
    __syncthreads();

    if (kb <= q0w + 31) {  // wave-uniform: this wave still has keys here
      // --- S = Q K^T: K frags shared across both m-tiles
      bf16x8 kf[4][2];
#pragma unroll
      for (int kt = 0; kt < 4; ++kt)
#pragma unroll
        for (int kc = 0; kc < 2; ++kc)
          kf[kt][kc] = *(const bf16x8*)(Ks + (size_t)(kt * 16 + m_) * KS +
                                        kc * 32 + quad * 8);
      floatx4 s[2][4];
#pragma unroll
      for (int mt = 0; mt < 2; ++mt)
#pragma unroll
        for (int kt = 0; kt < 4; ++kt) {
          floatx4 z = {0.f, 0.f, 0.f, 0.f};
          z = MFMA16(qf[mt][0], kf[kt][0], z);
          z = MFMA16(qf[mt][1], kf[kt][1], z);
          s[mt][kt] = z;
        }
      // --- online softmax; C/D layout: row = quad*4+r, col = m_
      const bool need_mask = (kb + 63 > q0w);
#pragma unroll
      for (int mt = 0; mt < 2; ++mt) {
#pragma unroll
        for (int r = 0; r < 4; ++r) {
          const int qr = q0w + mt * 16 + quad * 4 + r;
          float a[4];
#pragma unroll
          for (int kt = 0; kt < 4; ++kt) {
            a[kt] = s[mt][kt][r] * 0.125f;
            if (need_mask && (kb + kt * 16 + m_ > qr)) a[kt] = -1e30f;
          }
          float mx = fmaxf(fmaxf(a[0], a[1]), fmaxf(a[2], a[3]));
          mx = rmax16(mx);
          const float mnew = fmaxf(mrow[mt][r], mx);
          const float alpha = __expf(mrow[mt][r] - mnew);
          float p[4], psum = 0.f;
#pragma unroll
          for (int kt = 0; kt < 4; ++kt) { p[kt] = __expf(a[kt] - mnew); psum += p[kt]; }
          lrow[mt][r] = lrow[mt][r] * alpha + rsum16(psum);
          mrow[mt][r] = mnew;
#pragma unroll
          for (int nt = 0; nt < 4; ++nt) o[mt][nt][r] *= alpha;
#pragma unroll
          for (int kt = 0; kt < 4; ++kt)
            Pl[(size_t)((w * 2 + mt) * 16 + quad * 4 + r) * KS + kt * 16 + m_] =
                (bf16)p[kt];
        }
      }
      // --- PV: V frags shared across both m-tiles
      bf16x8 vf[4][2];
#pragma unroll
      for (int nt = 0; nt < 4; ++nt)
#pragma unroll
        for (int kc = 0; kc < 2; ++kc)
          vf[nt][kc] = *(const bf16x8*)(VT + (size_t)(nt * 16 + m_) * KS +
                                        kc * 32 + quad * 8);
#pragma unroll
      for (int mt = 0; mt < 2; ++mt) {
        const bf16* prow = Pl + (size_t)((w * 2 + mt) * 16 + m_) * KS;
        const bf16x8 pf0 = *(const bf16x8*)(prow + quad * 8);
        const bf16x8 pf1 = *(const bf16x8*)(prow + 32 + quad * 8);
#pragma unroll
        for (int nt = 0; nt < 4; ++nt) {
          o[mt][nt] = MFMA16(pf0, vf[nt][0], o[mt][nt]);
          o[mt][nt] = MFMA16(pf1, vf[nt][1], o[mt][nt]);
        }
      }
    }
    __syncthreads();
  }

  // --- normalize + store
#pragma unroll
  for (int mt = 0; mt < 2; ++mt)
#pragma unroll
    for (int r = 0; r < 4; ++r) {
      const float inv = 1.0f / lrow[mt][r];
      const int row = q0w + mt * 16 + quad * 4 + r;
      const size_t orow = ((size_t)b * 2048 + row) * 1024 + h * 64;
#pragma unroll
      for (int nt = 0; nt < 4; ++nt)
        attnout[orow + nt * 16 + m_] = (bf16)(o[mt][nt][r] * inv);
    }
}

// --------------------------------------------------------------------------
extern "C" void kernel_launch(void* const* d_in, const int* in_sizes, int n_in,
                              void* d_out, int out_size, void* d_ws, size_t ws_size,
                              hipStream_t stream) {
  (void)in_sizes; (void)n_in; (void)out_size; (void)ws_size;
  const float* x    = (const float*)d_in[0];   // [4,2048,1024]
  const float* Wqkv = (const float*)d_in[2];   // [1024,3072]
  const float* Wout = (const float*)d_in[3];   // [1024,1024]
  const float* bout = (const float*)d_in[4];   // [1024]
  float* out = (float*)d_out;                  // [4,2048,1024] fp32

  // ws: [qkv 48 MiB][attnout 16 MiB]; Wout_t reuses dead qkv space (2 MiB)
  bf16* qkv     = (bf16*)d_ws;
  bf16* attnout = (bf16*)((char*)d_ws + (size_t)8192 * 3072 * 2);
  bf16* Wout_t  = (bf16*)d_ws;
  // d_out doubles as prologue scratch (dead before GEMM2 writes it):
  bf16* xbf    = (bf16*)d_out;                        // 16 MiB
  bf16* Wqkv_t = (bf16*)d_out + (size_t)8192 * 1024;  // 6 MiB

  // prologue: convert + transpose
  convert_x<<<4096, 256, 0, stream>>>(x, xbf);  // 8192*1024/8/256
  transpose_w<<<dim3(3072 / 32, 1024 / 32), 256, 0, stream>>>(Wqkv, Wqkv_t, 1024, 3072);

  // GEMM1: qkv = x @ Wqkv  (M=8192, N=3072, K=1024)
  gemm_bt<true><<<dim3(24, 64), 256, 0, stream>>>(xbf, Wqkv_t, nullptr, qkv,
                                                  8192, 3072, 1024);
  // attention
  attn_fwd<<<dim3(16, 64), 256, 0, stream>>>(qkv, attnout);

  // Wout transpose into dead qkv region, then GEMM2 (fp32 out + bias)
  transpose_w<<<dim3(1024 / 32, 1024 / 32), 256, 0, stream>>>(Wout, Wout_t, 1024, 1024);
  gemm_bt<false><<<dim3(8, 64), 256, 0, stream>>>(attnout, Wout_t, bout, out,
                                                  8192, 1024, 1024);
}

// Round 4
// 315.481 us; speedup vs baseline: 2.5274x; 1.3490x over previous
//
#include <hip/hip_runtime.h>
#include <hip/hip_bf16.h>
#include <stdint.h>

// B=4, T=2048, C=1024, H=16, HD=64.  fp32 I/O.
// convert x->bf16, Wqkv->bf16[N][K] (d_out scratch) -> GEMM1 -> V-transpose
// (permuted) -> flash attn (paired q-tiles, uniform work) -> Wout^T -> GEMM2.

typedef __bf16 bf16;
typedef __bf16 bf16x4 __attribute__((ext_vector_type(4)));
typedef __bf16 bf16x8 __attribute__((ext_vector_type(8)));
typedef float floatx4 __attribute__((ext_vector_type(4)));

#define MFMA16(a, b, c) __builtin_amdgcn_mfma_f32_16x16x32_bf16(a, b, c, 0, 0, 0)

#if defined(__has_builtin)
#if __has_builtin(__builtin_amdgcn_global_load_lds)
#define HAS_GLL 1
#endif
#endif

#ifdef HAS_GLL
__device__ __forceinline__ void gll16(const bf16* g, bf16* l) {
  __builtin_amdgcn_global_load_lds(
      (const __attribute__((address_space(1))) unsigned int*)g,
      (__attribute__((address_space(3))) unsigned int*)l, 16, 0, 0);
}
#endif

static __device__ __forceinline__ float rmax16(float v) {
#pragma unroll
  for (int m = 1; m < 16; m <<= 1) v = fmaxf(v, __shfl_xor(v, m));
  return v;
}
static __device__ __forceinline__ float rsum16(float v) {
#pragma unroll
  for (int m = 1; m < 16; m <<= 1) v += __shfl_xor(v, m);
  return v;
}

// --------------------------------------------------------------------------
__global__ __launch_bounds__(256)
void convert_x(const float* __restrict__ in, bf16* __restrict__ out) {
  const size_t i = (size_t)blockIdx.x * 256 + threadIdx.x;
  const float4* p = (const float4*)in + i * 2;
  float4 a = p[0], b = p[1];
  bf16x8 v;
  v[0] = (bf16)a.x; v[1] = (bf16)a.y; v[2] = (bf16)a.z; v[3] = (bf16)a.w;
  v[4] = (bf16)b.x; v[5] = (bf16)b.y; v[6] = (bf16)b.z; v[7] = (bf16)b.w;
  *((bf16x8*)out + i) = v;
}

// --------------------------------------------------------------------------
__global__ __launch_bounds__(256)
void transpose_w(const float* __restrict__ W, bf16* __restrict__ Wt, int K, int N) {
  __shared__ bf16 tile[32][33];
  const int k0 = blockIdx.y * 32, n0 = blockIdx.x * 32;
  const int t = threadIdx.x;
  {
    const int r = t >> 3, c4 = (t & 7) * 4;
    float4 v = *(const float4*)(W + (size_t)(k0 + r) * N + n0 + c4);
    tile[r][c4 + 0] = (bf16)v.x;
    tile[r][c4 + 1] = (bf16)v.y;
    tile[r][c4 + 2] = (bf16)v.z;
    tile[r][c4 + 3] = (bf16)v.w;
  }
  __syncthreads();
  {
    const int nr = t >> 3, kc = (t & 7) * 4;
    bf16x4 o;
#pragma unroll
    for (int j = 0; j < 4; ++j) o[j] = tile[kc + j][nr];
    *(bf16x4*)(Wt + (size_t)(n0 + nr) * K + k0 + kc) = o;
  }
}

// --------------------------------------------------------------------------
// V transpose with per-64-key-block permutation kappa(c) = (c&3)*16 + (c>>2):
// vtp[bh][d][kb + c] = V[kb + kappa(c)][d].  Grid (32, 64).
// --------------------------------------------------------------------------
__global__ __launch_bounds__(256)
void vtrans(const bf16* __restrict__ qkv, bf16* __restrict__ vtp) {
  __shared__ bf16 tile[64][72];
  const int t = threadIdx.x;
  const int kb = blockIdx.x * 64;
  const int bh = blockIdx.y;
  const int b = bh >> 4, h = bh & 15;
  const bf16* Vp = qkv + (size_t)b * 2048 * 3072 + 2048 + h * 64;
#pragma unroll
  for (int i = 0; i < 2; ++i) {
    const int c = t + 256 * i, kk = c >> 3, dg = c & 7;
    *(bf16x8*)(&tile[kk][dg * 8]) =
        *(const bf16x8*)(Vp + (size_t)(kb + kk) * 3072 + dg * 8);
  }
  __syncthreads();
#pragma unroll
  for (int i = 0; i < 2; ++i) {
    const int c = t + 256 * i, d = c >> 3, g = c & 7;
    bf16x8 v;
#pragma unroll
    for (int j = 0; j < 8; ++j) {
      const int key = (j & 3) * 16 + 2 * g + (j >> 2);  // kappa(8g+j)
      v[j] = tile[key][d];
    }
    *(bf16x8*)(vtp + ((size_t)bh * 64 + d) * 2048 + kb + g * 8) = v;
  }
}

// --------------------------------------------------------------------------
// GEMM: C[M,N] = A[M,K] @ Bt[N,K]^T (+bias), bf16, fp32 accum.  128x128 tile,
// BK=64, 4 waves 2x2 (wave 64x64, 4x4 frags).  Linear LDS rows of 64 elems
// with XOR column-group swizzle (slot = g ^ (row&7)): gll-compatible dest,
// b128 frag reads at the 8-way floor.
// --------------------------------------------------------------------------
template <bool OUT_BF16>
__global__ __launch_bounds__(256, 3)
void gemm_bt(const bf16* __restrict__ A, const bf16* __restrict__ Bt,
             const float* __restrict__ bias, void* __restrict__ Cv,
             int M, int N, int K) {
  __shared__ __align__(16) bf16 As[128 * 64];
  __shared__ __align__(16) bf16 Bs[128 * 64];

  const int t = threadIdx.x, lane = t & 63, w = t >> 6;
  const int m_ = lane & 15, quad = lane >> 4;
  const int wm = w >> 1, wn = w & 1;
  const int m0 = blockIdx.y * 128, n0 = blockIdx.x * 128;

  floatx4 acc[4][4];
#pragma unroll
  for (int i = 0; i < 4; ++i)
#pragma unroll
    for (int j = 0; j < 4; ++j) {
      floatx4 z = {0.f, 0.f, 0.f, 0.f};
      acc[i][j] = z;
    }

  for (int k0 = 0; k0 < K; k0 += 64) {
#pragma unroll
    for (int i = 0; i < 4; ++i) {
      const int R0 = i * 32 + w * 8;
      const int R = R0 + (lane >> 3);
      const int sg = (lane & 7) ^ (R & 7);
      const bf16* ga = A + (size_t)(m0 + R) * K + k0 + sg * 8;
      const bf16* gb = Bt + (size_t)(n0 + R) * K + k0 + sg * 8;
#ifdef HAS_GLL
      gll16(ga, As + (size_t)R0 * 64);
      gll16(gb, Bs + (size_t)R0 * 64);
#else
      *(bf16x8*)(As + (size_t)R * 64 + (lane & 7) * 8) = *(const bf16x8*)ga;
      *(bf16x8*)(Bs + (size_t)R * 64 + (lane & 7) * 8) = *(const bf16x8*)gb;
#endif
    }
    __syncthreads();

#pragma unroll
    for (int kc = 0; kc < 2; ++kc) {
      bf16x8 af[4], bfr[4];
#pragma unroll
      for (int mt = 0; mt < 4; ++mt) {
        const int r = wm * 64 + mt * 16 + m_;
        const int slot = ((kc << 2) | quad) ^ (r & 7);
        af[mt] = *(const bf16x8*)(As + (size_t)r * 64 + slot * 8);
      }
#pragma unroll
      for (int nt = 0; nt < 4; ++nt) {
        const int rn = wn * 64 + nt * 16 + m_;
        const int slot = ((kc << 2) | quad) ^ (rn & 7);
        bfr[nt] = *(const bf16x8*)(Bs + (size_t)rn * 64 + slot * 8);
      }
#pragma unroll
      for (int mt = 0; mt < 4; ++mt)
#pragma unroll
        for (int nt = 0; nt < 4; ++nt)
          acc[mt][nt] = MFMA16(af[mt], bfr[nt], acc[mt][nt]);
    }
    __syncthreads();
  }

#pragma unroll
  for (int mt = 0; mt < 4; ++mt)
#pragma unroll
    for (int nt = 0; nt < 4; ++nt) {
      const int col = n0 + wn * 64 + nt * 16 + m_;
      const float bv = bias ? bias[col] : 0.f;
#pragma unroll
      for (int r = 0; r < 4; ++r) {
        const int row = m0 + wm * 64 + mt * 16 + quad * 4 + r;
        const float val = acc[mt][nt][r] + bv;
        if (OUT_BF16)
          ((bf16*)Cv)[(size_t)row * N + col] = (bf16)val;
        else
          ((float*)Cv)[(size_t)row * N + col] = val;
      }
    }
}

// --------------------------------------------------------------------------
// Flash attention, causal.  Block = 128 threads (2 waves x 32 queries),
// processes q-block pair {pb, 31-pb} (64 queries each) -> 33 chunks uniform.
// Grid (16, 64).  K staged [key][d] (stride 72), V^T staged [d][key-perm]
// (stride 72, b128 from vtp), P packed b64 writes (permuted cols).
// --------------------------------------------------------------------------
__global__ __launch_bounds__(128, 2)
void attn_fwd(const bf16* __restrict__ qkv, const bf16* __restrict__ vtp,
              bf16* __restrict__ attnout) {
  constexpr int KS = 72;
  __shared__ __align__(16) bf16 Ks[64 * KS];
  __shared__ __align__(16) bf16 VT[64 * KS];
  __shared__ __align__(16) bf16 Pl[64 * KS];  // [(w*2+mt)*16 + row][64 cols]

  const int t = threadIdx.x, lane = t & 63, w = t >> 6;  // w in {0,1}
  const int m_ = lane & 15, quad = lane >> 4;
  const int pb = blockIdx.x;  // 0..15
  const int bh = blockIdx.y;  // 0..63
  const int b = bh >> 4, h = bh & 15;

  const bf16* base = qkv + (size_t)b * 2048 * 3072;
  const bf16* Qp = base + h * 64;
  const bf16* Kp = base + 1024 + h * 64;
  const bf16* Vt = vtp + (size_t)bh * 64 * 2048;

#pragma unroll
  for (int pass = 0; pass < 2; ++pass) {
    const int qb = pass ? (31 - pb) : pb;  // 64-query block index
    const int q0w = qb * 64 + w * 32;

    bf16x8 qf[2][2];
#pragma unroll
    for (int mt = 0; mt < 2; ++mt)
#pragma unroll
      for (int kc = 0; kc < 2; ++kc)
        qf[mt][kc] = *(const bf16x8*)(Qp + (size_t)(q0w + mt * 16 + m_) * 3072 +
                                      kc * 32 + quad * 8);

    floatx4 o[2][4];
#pragma unroll
    for (int mt = 0; mt < 2; ++mt)
#pragma unroll
      for (int nt = 0; nt < 4; ++nt) {
        floatx4 z = {0.f, 0.f, 0.f, 0.f};
        o[mt][nt] = z;
      }
    float mrow[2][4], lrow[2][4];
#pragma unroll
    for (int mt = 0; mt < 2; ++mt)
#pragma unroll
      for (int r = 0; r < 4; ++r) { mrow[mt][r] = -1e30f; lrow[mt][r] = 0.f; }

    const int nch = qb + 1;
    for (int ch = 0; ch < nch; ++ch) {
      const int kb = ch * 64;
      // --- stage K [key][d]: 4 b128 per thread
#pragma unroll
      for (int i = 0; i < 4; ++i) {
        const int c = t + 128 * i, kk = c >> 3, dg = c & 7;
        *(bf16x8*)(Ks + (size_t)kk * KS + dg * 8) =
            *(const bf16x8*)(Kp + (size_t)(kb + kk) * 3072 + dg * 8);
      }
      // --- stage V^T [d][key-perm]: 4 b128 per thread (from vtp)
#pragma unroll
      for (int i = 0; i < 4; ++i) {
        const int c = t + 128 * i, d = c >> 3, g = c & 7;
        *(bf16x8*)(VT + (size_t)d * KS + g * 8) =
            *(const bf16x8*)(Vt + (size_t)d * 2048 + kb + g * 8);
      }
      __syncthreads();

      if (kb <= q0w + 31) {
        // --- S = Q K^T
        bf16x8 kf[4][2];
#pragma unroll
        for (int kt = 0; kt < 4; ++kt)
#pragma unroll
          for (int kc = 0; kc < 2; ++kc)
            kf[kt][kc] = *(const bf16x8*)(Ks + (size_t)(kt * 16 + m_) * KS +
                                          kc * 32 + quad * 8);
        floatx4 s[2][4];
#pragma unroll
        for (int mt = 0; mt < 2; ++mt)
#pragma unroll
          for (int kt = 0; kt < 4; ++kt) {
            floatx4 z = {0.f, 0.f, 0.f, 0.f};
            z = MFMA16(qf[mt][0], kf[kt][0], z);
            z = MFMA16(qf[mt][1], kf[kt][1], z);
            s[mt][kt] = z;
          }
        // --- online softmax; S layout: row=quad*4+r (query), col=m_ (key)
        const bool need_mask = (kb + 63 > q0w);
#pragma unroll
        for (int mt = 0; mt < 2; ++mt) {
#pragma unroll
          for (int r = 0; r < 4; ++r) {
            const int qr = q0w + mt * 16 + quad * 4 + r;
            float a[4];
#pragma unroll
            for (int kt = 0; kt < 4; ++kt) {
              a[kt] = s[mt][kt][r] * 0.125f;
              if (need_mask && (kb + kt * 16 + m_ > qr)) a[kt] = -1e30f;
            }
            float mx = fmaxf(fmaxf(a[0], a[1]), fmaxf(a[2], a[3]));
            mx = rmax16(mx);
            const float mnew = fmaxf(mrow[mt][r], mx);
            const float alpha = __expf(mrow[mt][r] - mnew);
            float p[4], psum = 0.f;
#pragma unroll
            for (int kt = 0; kt < 4; ++kt) { p[kt] = __expf(a[kt] - mnew); psum += p[kt]; }
            lrow[mt][r] = lrow[mt][r] * alpha + rsum16(psum);
            mrow[mt][r] = mnew;
#pragma unroll
            for (int nt = 0; nt < 4; ++nt) o[mt][nt][r] *= alpha;
            // packed P write: storage col c = m_*4 + kt  (kappa(c)=kt*16+m_)
            bf16x4 pw;
#pragma unroll
            for (int kt = 0; kt < 4; ++kt) pw[kt] = (bf16)p[kt];
            *(bf16x4*)(Pl + (size_t)((w * 2 + mt) * 16 + quad * 4 + r) * KS +
                       m_ * 4) = pw;
          }
        }
        // --- PV (keys in permuted storage order, consistent with VT)
        bf16x8 vf[4][2];
#pragma unroll
        for (int nt = 0; nt < 4; ++nt)
#pragma unroll
          for (int kc = 0; kc < 2; ++kc)
            vf[nt][kc] = *(const bf16x8*)(VT + (size_t)(nt * 16 + m_) * KS +
                                          kc * 32 + quad * 8);
#pragma unroll
        for (int mt = 0; mt < 2; ++mt) {
          const bf16* prow = Pl + (size_t)((w * 2 + mt) * 16 + m_) * KS;
          const bf16x8 pf0 = *(const bf16x8*)(prow + quad * 8);
          const bf16x8 pf1 = *(const bf16x8*)(prow + 32 + quad * 8);
#pragma unroll
          for (int nt = 0; nt < 4; ++nt) {
            o[mt][nt] = MFMA16(pf0, vf[nt][0], o[mt][nt]);
            o[mt][nt] = MFMA16(pf1, vf[nt][1], o[mt][nt]);
          }
        }
      }
      __syncthreads();
    }

    // --- normalize + store
#pragma unroll
    for (int mt = 0; mt < 2; ++mt)
#pragma unroll
      for (int r = 0; r < 4; ++r) {
        const float inv = 1.0f / lrow[mt][r];
        const int row = q0w + mt * 16 + quad * 4 + r;
        const size_t orow = ((size_t)b * 2048 + row) * 1024 + h * 64;
#pragma unroll
        for (int nt = 0; nt < 4; ++nt)
          attnout[orow + nt * 16 + m_] = (bf16)(o[mt][nt][r] * inv);
      }
  }
}

// --------------------------------------------------------------------------
extern "C" void kernel_launch(void* const* d_in, const int* in_sizes, int n_in,
                              void* d_out, int out_size, void* d_ws, size_t ws_size,
                              hipStream_t stream) {
  (void)in_sizes; (void)n_in; (void)out_size; (void)ws_size;
  const float* x    = (const float*)d_in[0];
  const float* Wqkv = (const float*)d_in[2];
  const float* Wout = (const float*)d_in[3];
  const float* bout = (const float*)d_in[4];
  float* out = (float*)d_out;

  // d_ws: qkv 48 MiB @0, attnout 16 MiB @48.  Wout_t reuses dead qkv space.
  bf16* qkv     = (bf16*)d_ws;
  bf16* attnout = (bf16*)((char*)d_ws + (size_t)8192 * 3072 * 2);
  bf16* Wout_t  = (bf16*)d_ws;
  // d_out (32 MiB) as prologue scratch, dead before GEMM2 writes it:
  bf16* xbf    = (bf16*)d_out;                        // 16 MiB
  bf16* Wqkv_t = (bf16*)d_out + (size_t)8192 * 1024;  // 6 MiB (dead after G1)
  bf16* vtp    = (bf16*)d_out + (size_t)8192 * 1024;  // 16 MiB (after G1)

  convert_x<<<4096, 256, 0, stream>>>(x, xbf);
  transpose_w<<<dim3(96, 32), 256, 0, stream>>>(Wqkv, Wqkv_t, 1024, 3072);

  // GEMM1: qkv = x @ Wqkv  (M=8192, N=3072, K=1024)
  gemm_bt<true><<<dim3(24, 64), 256, 0, stream>>>(xbf, Wqkv_t, nullptr, qkv,
                                                  8192, 3072, 1024);
  // V transpose (permuted), then attention
  vtrans<<<dim3(32, 64), 256, 0, stream>>>(qkv, vtp);
  attn_fwd<<<dim3(16, 64), 128, 0, stream>>>(qkv, vtp, attnout);

  // Wout^T into dead qkv region, then GEMM2 (fp32 out + bias)
  transpose_w<<<dim3(32, 32), 256, 0, stream>>>(Wout, Wout_t, 1024, 1024);
  gemm_bt<false><<<dim3(8, 64), 256, 0, stream>>>(attnout, Wout_t, bout, out,
                                                  8192, 1024, 1024);
}